// Round 16
// baseline (557.115 us; speedup 1.0000x reference)
//
#include <hip/hip_runtime.h>
#include <stdint.h>

// UnarySqrt scan, T=64 steps, N=2^20 channels, exact {0,1} floats.
//   per step: p = x*(1-tr); out = tr + p; tr' = p
//
// R1..R15: every issue structure lands at ~2.4 TB/s, while the harness's own
// restore copy (512 MB mixed R+W) must run at ~6.3 TB/s in the same timed
// loop (overhead arithmetic only adds up that way). Difference: the copy's
// instantaneous address window is a few MB (linear sweep); ours spans the
// whole 256 MB because unpaced blocks drift across the 64 x 4 MB rows ->
// DRAM page scatter at ~1/3 peak.
//
// This round bounds the window: R14/R15 body (8-row register batches with
// asm-tie materialization, NT loads / plain stores per R15's win) + a
// TIMEOUT-SAFE pacing barrier between 8-row chunks. Block leaders bump a
// per-chunk counter and spin (bounded!) until all blocks arrive; the
// recurrence is thread-private so correctness NEVER depends on the barrier
// -- worst case it wastes ~8 us/chunk. Chip-wide window collapses to
// <= 2 chunks ~ 64 MB. Counters live in d_ws, zeroed by a tiny init kernel
// each launch (d_ws is re-poisoned to 0xAA before every timed call).

typedef float v4f __attribute__((ext_vector_type(4)));

#define RPC 8      // rows per chunk
#define NCHK 8     // chunks (RPC * NCHK = 64 = T)

__global__ void pace_init(int* cnt) {
    if (threadIdx.x < 16) cnt[threadIdx.x] = 0;
}

__global__ __launch_bounds__(1024) void UnarySqrt_kernel(
    const v4f* __restrict__ in,      // [64, stride]
    const v4f* __restrict__ trace0,  // [stride]
    v4f* __restrict__ out,           // [64, stride]
    int stride,                       // N/4
    int* __restrict__ cnt,            // [16] zeroed pacing counters
    int nblocks)
{
    const int idx = blockIdx.x * blockDim.x + threadIdx.x;
    if (idx >= stride) return;

    v4f tr = trace0[idx];

    for (int c = 0; c < NCHK; ++c) {
        // ---- load phase: 8 independent NT dwordx4 loads, all in flight ----
        v4f buf[RPC];
        #pragma unroll
        for (int j = 0; j < RPC; ++j) {
            buf[j] = __builtin_nontemporal_load(
                &in[(size_t)(c * RPC + j) * (size_t)stride + (size_t)idx]);
        }
        asm volatile("" : "+v"(buf[0]), "+v"(buf[1]), "+v"(buf[2]), "+v"(buf[3]),
                          "+v"(buf[4]), "+v"(buf[5]), "+v"(buf[6]), "+v"(buf[7]));
        // ---- compute + store phase: plain stores (L2/L3 write-allocate) ----
        #pragma unroll
        for (int j = 0; j < RPC; ++j) {
            v4f p = buf[j] * (1.0f - tr);
            v4f o = tr + p;
            out[(size_t)(c * RPC + j) * (size_t)stride + (size_t)idx] = o;
            tr = p;
        }
        // ---- pacing barrier (performance only; timeout-safe) ----
        if (c + 1 < NCHK) {
            __syncthreads();
            if (threadIdx.x == 0) {
                __hip_atomic_fetch_add(&cnt[c], 1, __ATOMIC_RELAXED,
                                       __HIP_MEMORY_SCOPE_AGENT);
                int lim = 150;  // hard bound: ~8 us max spin, no deadlock ever
                while (__hip_atomic_load(&cnt[c], __ATOMIC_RELAXED,
                                         __HIP_MEMORY_SCOPE_AGENT) < nblocks
                       && --lim) {
                    __builtin_amdgcn_s_sleep(2);
                }
            }
            __syncthreads();
        }
    }
}

// Generic fallback (correct for any T, N%4==0).
__global__ __launch_bounds__(256) void UnarySqrt_generic(
    const v4f* __restrict__ in, const v4f* __restrict__ trace0,
    v4f* __restrict__ out, int stride, int T)
{
    int idx = blockIdx.x * blockDim.x + threadIdx.x;
    if (idx >= stride) return;
    v4f tr = trace0[idx];
    for (int t = 0; t < T; ++t) {
        v4f x = in[(size_t)t * stride + idx];
        v4f p = x * (1.0f - tr);
        out[(size_t)t * stride + idx] = tr + p;
        tr = p;
    }
}

extern "C" void kernel_launch(void* const* d_in, const int* in_sizes, int n_in,
                              void* d_out, int out_size, void* d_ws, size_t ws_size,
                              hipStream_t stream) {
    const float* bits   = (const float*)d_in[0];  // [T, N]
    const float* trace0 = (const float*)d_in[1];  // [N]

    int N = in_sizes[1];
    int T = in_sizes[0] / N;
    int stride = N / 4;

    if (T == 64 && (stride % 1024) == 0) {
        int grid = stride / 1024;  // 256 blocks at N=2^20 -> 1 block/CU
        int* cnt = (int*)d_ws;
        pace_init<<<1, 64, 0, stream>>>(cnt);
        UnarySqrt_kernel<<<grid, 1024, 0, stream>>>(
            (const v4f*)bits, (const v4f*)trace0, (v4f*)d_out, stride, cnt, grid);
    } else {
        int block = 256;
        int grid = (stride + block - 1) / block;
        UnarySqrt_generic<<<grid, block, 0, stream>>>(
            (const v4f*)bits, (const v4f*)trace0, (v4f*)d_out, stride, T);
    }
}

// Round 17
// 510.698 us; speedup vs baseline: 1.0909x; 1.0909x over previous
//
#include <hip/hip_runtime.h>
#include <stdint.h>

// UnarySqrt scan, T=64 steps, N=2^20 channels, exact {0,1} floats.
//   per step: p = x*(1-tr); out = tr + p; tr' = p
//
// DIAGNOSTIC ROUND. Six structures (R1..R16) all sit at 2.45-2.6 TB/s mixed
// R+W; the only measured 6.5 TB/s dispatches (harness fills) are WRITE-ONLY.
// The claim "mixed traffic can run at 6.4 TB/s here" rests on an unmeasured
// inference about the harness restore copy. This round measures it directly:
//   1. copy_probe: one-shot copyBuffer mimicry (1 v4f per thread, no loop,
//      no recurrence) moving the 256 MB input into d_ws. Its rocprof row
//      (dur_us, hbm_gbps, ~512 MB hbm_bytes) IS the mixed-stream ceiling for
//      a compute kernel in this exact timed loop.
//   2. main kernel = R15's best (NT loads, plain stores, 1024-thr blocks,
//      depth-2 prefetch) reading from the fresh d_ws copy (L3-hot).
// If probe >= 5 TB/s: ceiling is real, keep hunting the one-shot/loop gap.
// If probe ~ 2.5 TB/s: mixed traffic is environmentally capped -> R15 was
// the roofline; revert and declare next round.

typedef float v4f __attribute__((ext_vector_type(4)));

__global__ __launch_bounds__(256) void copy_probe(
    const v4f* __restrict__ src, v4f* __restrict__ dst, int n4)
{
    int i = blockIdx.x * blockDim.x + threadIdx.x;
    if (i < n4) dst[i] = src[i];
}

__global__ __launch_bounds__(1024) void UnarySqrt_kernel(
    const v4f* __restrict__ in,      // [64, stride] (the d_ws copy)
    const v4f* __restrict__ trace0,  // [stride]
    v4f* __restrict__ out,           // [64, stride]
    int stride)                       // N/4
{
    const int idx = blockIdx.x * blockDim.x + threadIdx.x;
    if (idx >= stride) return;

    v4f tr = trace0[idx];
    v4f x  = __builtin_nontemporal_load(&in[idx]);  // prefetch row 0

    #pragma unroll 8
    for (int t = 0; t < 64; ++t) {
        v4f xn;
        if (t + 1 < 64) {
            xn = __builtin_nontemporal_load(
                &in[(size_t)(t + 1) * (size_t)stride + (size_t)idx]);
        }
        v4f p = x * (1.0f - tr);
        v4f o = tr + p;
        out[(size_t)t * (size_t)stride + (size_t)idx] = o;  // plain: allocate
        tr = p;
        x = xn;
    }
}

// Generic fallback (correct for any T, N%4==0), reads d_in directly.
__global__ __launch_bounds__(256) void UnarySqrt_generic(
    const v4f* __restrict__ in, const v4f* __restrict__ trace0,
    v4f* __restrict__ out, int stride, int T)
{
    int idx = blockIdx.x * blockDim.x + threadIdx.x;
    if (idx >= stride) return;
    v4f tr = trace0[idx];
    for (int t = 0; t < T; ++t) {
        v4f x = in[(size_t)t * stride + idx];
        v4f p = x * (1.0f - tr);
        out[(size_t)t * stride + idx] = tr + p;
        tr = p;
    }
}

extern "C" void kernel_launch(void* const* d_in, const int* in_sizes, int n_in,
                              void* d_out, int out_size, void* d_ws, size_t ws_size,
                              hipStream_t stream) {
    const float* bits   = (const float*)d_in[0];  // [T, N]
    const float* trace0 = (const float*)d_in[1];  // [N]

    int N = in_sizes[1];
    int T = in_sizes[0] / N;
    int stride = N / 4;
    size_t in_bytes = (size_t)in_sizes[0] * 4;

    if (T == 64 && (stride % 1024) == 0 && ws_size >= in_bytes) {
        int n4 = in_sizes[0] / 4;  // total v4f elements in input
        copy_probe<<<(n4 + 255) / 256, 256, 0, stream>>>(
            (const v4f*)bits, (v4f*)d_ws, n4);
        int grid = stride / 1024;  // 256 blocks -> 1 block/CU
        UnarySqrt_kernel<<<grid, 1024, 0, stream>>>(
            (const v4f*)d_ws, (const v4f*)trace0, (v4f*)d_out, stride);
    } else {
        int block = 256;
        int grid = (stride + block - 1) / block;
        UnarySqrt_generic<<<grid, block, 0, stream>>>(
            (const v4f*)bits, (const v4f*)trace0, (v4f*)d_out, stride, T);
    }
}